// Round 4
// baseline (457.543 us; speedup 1.0000x reference)
//
#include <hip/hip_runtime.h>

// Problem constants
#define DD 128    // nodes / input dim
#define HH 512    // hidden
#define NN 2048   // batch rows
#define NT 64     // rows per block tile
#define PLD 516   // pack LDS leading dim

typedef __bf16 bf16x8 __attribute__((ext_vector_type(8)));
typedef __bf16 bf16x4 __attribute__((ext_vector_type(4)));
typedef float  floatx4 __attribute__((ext_vector_type(4)));

// ---------------------------------------------------------------------------
// x (fp32 row-major) -> xb (bf16 row-major). 2048x128, 16B/thread.
// ---------------------------------------------------------------------------
__global__ void cvt_x(const float* __restrict__ x, __bf16* __restrict__ xb) {
    int t = blockIdx.x * blockDim.x + threadIdx.x;
    float4 v = *(const float4*)(x + (size_t)t * 4);
    bf16x4 o;
    o[0] = (__bf16)v.x; o[1] = (__bf16)v.y; o[2] = (__bf16)v.z; o[3] = (__bf16)v.w;
    *(bf16x4*)(xb + (size_t)t * 4) = o;
}

// ---------------------------------------------------------------------------
// Pack W[d][K][H] fp32 -> bf16 MFMA fragment order via LDS transpose.
//   Wp[((((d*32+ct)*nks+ks)*4+q)*16+c)*8+j] = bf16(W[d][ks*32+q*8+j][ct*16+c])
// This layout serves BOTH as a B-frag (B[k][n]=W[k][n]) and as an A-frag of
// W^T (A[m][k]=W[k][m]) -- per-lane patterns are identical.
// ---------------------------------------------------------------------------
__global__ void pack_w(const float* __restrict__ W, __bf16* __restrict__ Wp, int nks) {
    __shared__ __bf16 Ls[32 * PLD];
    const int d  = blockIdx.x / nks;
    const int ks = blockIdx.x % nks;
    const int tid = threadIdx.x;
    const float* src = W + ((size_t)(d * nks + ks) * 32) * HH;

#pragma unroll
    for (int it = 0; it < 16; ++it) {
        int e = (it * 256 + tid) * 4;
        float4 v = *(const float4*)(src + e);
        bf16x4 o;
        o[0] = (__bf16)v.x; o[1] = (__bf16)v.y; o[2] = (__bf16)v.z; o[3] = (__bf16)v.w;
        *(bf16x4*)(Ls + (e >> 9) * PLD + (e & 511)) = o;
    }
    __syncthreads();

#pragma unroll
    for (int it = 0; it < 8; ++it) {
        int ch = it * 256 + tid;
        int c  = ch & 15;
        int q  = (ch >> 4) & 3;
        int ct = ch >> 6;
        bf16x8 v;
#pragma unroll
        for (int j = 0; j < 8; ++j)
            v[j] = Ls[(q * 8 + j) * PLD + ct * 16 + c];
        *(bf16x8*)(Wp + ((size_t)(d * 32 + ct) * nks + ks) * 512 + (ch & 63) * 8) = v;
    }
}

// ---------------------------------------------------------------------------
// Fused per-(d, row-tile) MLP, TRANSPOSED operand order:
//   mfma(Wfrag, Xfrag) => D = W^T . X^T = (X.W)^T, so lane lc holds OUTPUT ROW
//   lc with 4 consecutive columns per reg group -> h1 stores are ds_write_b64.
// h1s: 64x512 bf16, XOR-swizzled 16B chunks (chunk ^= row&7) -> <=2-way banks.
//   write: (row, col0=64w+16mt+4lq) -> [row*512 + ((8w+2mt+(lq>>1))^(row&7))*8
//                                       + (lq&1)*4]
//   read (B-frag, k=32ks+8lq..+8):   [row*512 + ((4ks+lq)^(row&7))*8]
// Register budget: 64 acc (AGPR) + 32 frag + ~20 addr fits 64V+64A of (512,4).
// ---------------------------------------------------------------------------
__launch_bounds__(512, 4)
__global__ void grandag_main(const __bf16* __restrict__ xb,
                             const __bf16* __restrict__ W0p,
                             const __bf16* __restrict__ W1p,
                             const float* __restrict__ W2,
                             float* __restrict__ out) {
    __shared__ __bf16 h1s[NT * HH];   // 65536 B
    __shared__ float  outp[NT];       // -> 2 blocks/CU

    const int b  = blockIdx.x;
    // XCD swizzle: d % 8 == blockIdx % 8 -> all 32 tiles of a d on one XCD
    const int d  = ((b >> 8) << 3) | (b & 7);
    const int n0 = ((b >> 3) & 31) * NT;

    const int tid = threadIdx.x;
    const int w   = tid >> 6;   // wave 0..7: owns h-cols [w*64, w*64+64)
    const int l   = tid & 63;
    const int lc  = l & 15;     // C/D col = batch row (transposed form)
    const int lq  = l >> 4;     // k-quad
    const int sw  = lc & 7;     // LDS swizzle key (row-derived)

    const int ksz = d >> 5;          // k-slice containing column d of X
    const int lqz = (d >> 3) & 3;    // quad containing it
    const int jz  = d & 7;           // element containing it

    if (tid < NT) outp[tid] = 0.f;

    // ---- phase 1: acc[mt][nt] = W0[d]^T (cols 64w+16mt..) . Xmask^T (rows 16nt..)
    {
        floatx4 acc[4][4] = {};
#pragma unroll
        for (int ks = 0; ks < 4; ks++) {
            bf16x8 xf[4], wf[4];
#pragma unroll
            for (int nt = 0; nt < 4; nt++)
                xf[nt] = *(const bf16x8*)(xb + (size_t)(n0 + 16 * nt + lc) * DD + ks * 32 + lq * 8);
            if (ks == ksz && lq == lqz) {   // zero column d of X (the mask)
#pragma unroll
                for (int nt = 0; nt < 4; nt++)
#pragma unroll
                    for (int j = 0; j < 8; j++)
                        if (j == jz) xf[nt][j] = (__bf16)0.f;
            }
#pragma unroll
            for (int mt = 0; mt < 4; mt++)
                wf[mt] = *(const bf16x8*)(W0p +
                    ((((size_t)d * 32 + (w * 4 + mt)) * 4 + ks) * 64 + lq * 16 + lc) * 8);
#pragma unroll
            for (int mt = 0; mt < 4; mt++)
#pragma unroll
                for (int nt = 0; nt < 4; nt++)
                    acc[mt][nt] = __builtin_amdgcn_mfma_f32_16x16x32_bf16(
                        wf[mt], xf[nt], acc[mt][nt], 0, 0, 0);
        }
        // epilogue: lane holds h1[row=16nt+lc][col=64w+16mt+4lq+g], g=0..3
#pragma unroll
        for (int mt = 0; mt < 4; mt++) {
            int chunk = 8 * w + 2 * mt + (lq >> 1);
#pragma unroll
            for (int nt = 0; nt < 4; nt++) {
                bf16x4 o;
#pragma unroll
                for (int g = 0; g < 4; g++) {
                    float v = acc[mt][nt][g];
                    o[g] = (__bf16)fmaxf(v, 0.01f * v);   // leaky relu
                }
                *(bf16x4*)(h1s + (16 * nt + lc) * HH + ((chunk ^ sw) << 3) + ((lq & 1) << 2)) = o;
            }
        }
    }
    __syncthreads();

    // ---- phase 2: acc2[mt][nt] = W1[d]^T (cols 64w+16mt..) . h1^T (rows 16nt..)
    floatx4 acc2[4][4] = {};
#pragma unroll
    for (int ks = 0; ks < 16; ks++) {
        bf16x8 hf[4], wf[4];
#pragma unroll
        for (int nt = 0; nt < 4; nt++)
            hf[nt] = *(const bf16x8*)(h1s + (16 * nt + lc) * HH + (((4 * ks + lq) ^ sw) << 3));
#pragma unroll
        for (int mt = 0; mt < 4; mt++)
            wf[mt] = *(const bf16x8*)(W1p +
                ((((size_t)d * 32 + (w * 4 + mt)) * 16 + ks) * 64 + lq * 16 + lc) * 8);
#pragma unroll
        for (int mt = 0; mt < 4; mt++)
#pragma unroll
            for (int nt = 0; nt < 4; nt++)
                acc2[mt][nt] = __builtin_amdgcn_mfma_f32_16x16x32_bf16(
                    wf[mt], hf[nt], acc2[mt][nt], 0, 0, 0);
    }

    // ---- phase 3: out = leaky(h2) @ W2[d]; lane lc holds rows 16nt+lc
    floatx4 w2v[4];
#pragma unroll
    for (int mt = 0; mt < 4; mt++)
        w2v[mt] = *(const floatx4*)(W2 + (size_t)d * HH + w * 64 + mt * 16 + lq * 4);
#pragma unroll
    for (int nt = 0; nt < 4; nt++) {
        float s = 0.f;
#pragma unroll
        for (int mt = 0; mt < 4; mt++)
#pragma unroll
            for (int g = 0; g < 4; g++) {
                float v = acc2[mt][nt][g];
                s += fmaxf(v, 0.01f * v) * w2v[mt][g];
            }
        // sum the 4 lq-groups holding the same row
        s += __shfl_xor(s, 16, 64);
        s += __shfl_xor(s, 32, 64);
        if (l < 16) atomicAdd(&outp[16 * nt + lc], s);   // cross-wave reduce
    }
    __syncthreads();
    if (tid < NT) out[(size_t)(n0 + tid) * DD + d] = outp[tid];
}

// ---------------------------------------------------------------------------
extern "C" void kernel_launch(void* const* d_in, const int* in_sizes, int n_in,
                              void* d_out, int out_size, void* d_ws, size_t ws_size,
                              hipStream_t stream) {
    const float* x  = (const float*)d_in[0];
    const float* W0 = (const float*)d_in[1];
    const float* W1 = (const float*)d_in[2];
    const float* W2 = (const float*)d_in[3];
    float* out = (float*)d_out;

    __bf16* W0p = (__bf16*)d_ws;                                          // 16.8 MB
    __bf16* W1p = (__bf16*)((char*)d_ws + (size_t)DD * DD * HH * 2);      // 67.1 MB
    __bf16* xb  = (__bf16*)((char*)d_ws + (size_t)DD * DD * HH * 2
                                        + (size_t)DD * HH * HH * 2);      // 0.5 MB

    cvt_x<<<dim3(NN * DD / (256 * 4)), 256, 0, stream>>>(x, xb);
    pack_w<<<dim3(DD * (DD / 32)), 256, 0, stream>>>(W0, W0p, DD / 32);   // 512 blocks
    pack_w<<<dim3(DD * (HH / 32)), 256, 0, stream>>>(W1, W1p, HH / 32);   // 2048 blocks

    grandag_main<<<dim3(DD * (NN / NT)), 512, 0, stream>>>(xb, W0p, W1p, W2, out);
}

// Round 5
// 408.042 us; speedup vs baseline: 1.1213x; 1.1213x over previous
//
#include <hip/hip_runtime.h>

// Problem constants
#define DD 128    // nodes / input dim
#define HH 512    // hidden
#define NN 2048   // batch rows
#define NT 64     // rows per block tile
#define PLD 516   // pack LDS leading dim

typedef __bf16 bf16x8 __attribute__((ext_vector_type(8)));
typedef __bf16 bf16x4 __attribute__((ext_vector_type(4)));
typedef float  floatx4 __attribute__((ext_vector_type(4)));

// ---------------------------------------------------------------------------
// x (fp32 row-major) -> xb (bf16 row-major). 2048x128, 16B/thread.
// ---------------------------------------------------------------------------
__global__ void cvt_x(const float* __restrict__ x, __bf16* __restrict__ xb) {
    int t = blockIdx.x * blockDim.x + threadIdx.x;
    float4 v = *(const float4*)(x + (size_t)t * 4);
    bf16x4 o;
    o[0] = (__bf16)v.x; o[1] = (__bf16)v.y; o[2] = (__bf16)v.z; o[3] = (__bf16)v.w;
    *(bf16x4*)(xb + (size_t)t * 4) = o;
}

// ---------------------------------------------------------------------------
// Pack W[d][K][H] fp32 -> bf16 MFMA fragment order via LDS transpose.
//   Wp[((((d*32+ct)*nks+ks)*4+q)*16+c)*8+j] = bf16(W[d][ks*32+q*8+j][ct*16+c])
// Serves both as B-frag (B[k][n]) and as A-frag of W^T (A[m][k]) -- identical
// per-lane patterns.
// ---------------------------------------------------------------------------
__global__ void pack_w(const float* __restrict__ W, __bf16* __restrict__ Wp, int nks) {
    __shared__ __bf16 Ls[32 * PLD];
    const int d  = blockIdx.x / nks;
    const int ks = blockIdx.x % nks;
    const int tid = threadIdx.x;
    const float* src = W + ((size_t)(d * nks + ks) * 32) * HH;

#pragma unroll
    for (int it = 0; it < 16; ++it) {
        int e = (it * 256 + tid) * 4;
        float4 v = *(const float4*)(src + e);
        bf16x4 o;
        o[0] = (__bf16)v.x; o[1] = (__bf16)v.y; o[2] = (__bf16)v.z; o[3] = (__bf16)v.w;
        *(bf16x4*)(Ls + (e >> 9) * PLD + (e & 511)) = o;
    }
    __syncthreads();

#pragma unroll
    for (int it = 0; it < 8; ++it) {
        int ch = it * 256 + tid;
        int c  = ch & 15;
        int q  = (ch >> 4) & 3;
        int ct = ch >> 6;
        bf16x8 v;
#pragma unroll
        for (int j = 0; j < 8; ++j)
            v[j] = Ls[(q * 8 + j) * PLD + ct * 16 + c];
        *(bf16x8*)(Wp + ((size_t)(d * 32 + ct) * nks + ks) * 512 + (ch & 63) * 8) = v;
    }
}

// ---------------------------------------------------------------------------
// Fused per-(d, row-tile) MLP, transposed operand order:
//   mfma(Wfrag, Xfrag) => D = (X.W)^T: lane lc holds output ROW lc, 4
//   consecutive cols per reg group -> h1 stores are ds_write_b64.
// VGPR discipline (the (512,4) cap = 64V+64A): wf[4] resident, xf/hf loaded
// ONE at a time; uniform address terms separated into base pointers (SGPR);
// epilogue processes one (mt,nt) at a time. Round-4's 32 live frag regs +
// 16 store addrs spilled 249 MB; this version's worst-case live set ~60 V.
// ---------------------------------------------------------------------------
__launch_bounds__(512, 4)
__global__ void grandag_main(const __bf16* __restrict__ xb,
                             const __bf16* __restrict__ W0p,
                             const __bf16* __restrict__ W1p,
                             const float* __restrict__ W2,
                             float* __restrict__ out) {
    __shared__ __bf16 h1s[NT * HH];   // 65536 B
    __shared__ float  outp[NT];       // -> 2 blocks/CU

    const int b  = blockIdx.x;
    // XCD swizzle: d % 8 == blockIdx % 8 -> all 32 tiles of a d on one XCD
    const int d  = ((b >> 8) << 3) | (b & 7);
    const int n0 = ((b >> 3) & 31) * NT;

    const int tid = threadIdx.x;
    const int w   = tid >> 6;   // wave 0..7: owns h-cols [w*64, w*64+64)
    const int l   = tid & 63;
    const int lc  = l & 15;     // C/D col = batch row (transposed form)
    const int lq  = l >> 4;     // k-quad
    const int sw  = lc & 7;     // LDS swizzle key (row-derived)
    const int lane16 = lq * 16 + lc;   // per-lane frag index (8-elem units)

    const int ksz = d >> 5;          // k-slice containing column d of X
    const int lqz = (d >> 3) & 3;    // quad containing it
    const int jz  = d & 7;           // element containing it

    if (tid < NT) outp[tid] = 0.f;

    // ---- phase 1: acc[mt][nt] = W0[d]^T (cols 64w+16mt..) . Xmask^T (rows 16nt..)
    {
        floatx4 acc[4][4] = {};
        // base pointers: uniform part in SGPRs, lane16 part in one VGPR
        const __bf16* W0b = W0p + ((size_t)(d * 32 + w * 4) * 4) * 512 + (size_t)lane16 * 8;
        const __bf16* xbb = xb + (size_t)(n0 + lc) * DD + lq * 8;
#pragma unroll
        for (int ks = 0; ks < 4; ks++) {
            bf16x8 wf[4];
#pragma unroll
            for (int mt = 0; mt < 4; mt++)
                wf[mt] = *(const bf16x8*)(W0b + (size_t)(mt * 4 + ks) * 512);
            const bool domask = (ks == ksz) && (lq == lqz);
#pragma unroll
            for (int nt = 0; nt < 4; nt++) {
                bf16x8 xf = *(const bf16x8*)(xbb + (size_t)(16 * nt) * DD + ks * 32);
                if (domask) {
#pragma unroll
                    for (int j = 0; j < 8; j++)
                        if (j == jz) xf[j] = (__bf16)0.f;
                }
#pragma unroll
                for (int mt = 0; mt < 4; mt++)
                    acc[mt][nt] = __builtin_amdgcn_mfma_f32_16x16x32_bf16(
                        wf[mt], xf, acc[mt][nt], 0, 0, 0);
            }
        }
        // epilogue: lane holds h1[row=16nt+lc][col=64w+16mt+4lq+g], g=0..3
        // h1s layout: row-major 512, 16B chunks XOR-swizzled by row&7.
#pragma unroll
        for (int mt = 0; mt < 4; mt++) {
            const int chunk = 8 * w + 2 * mt + (lq >> 1);
#pragma unroll
            for (int nt = 0; nt < 4; nt++) {
                bf16x4 o;
#pragma unroll
                for (int g = 0; g < 4; g++) {
                    float v = acc[mt][nt][g];
                    o[g] = (__bf16)fmaxf(v, 0.01f * v);   // leaky relu
                }
                *(bf16x4*)(h1s + (16 * nt + lc) * HH + ((chunk ^ sw) << 3) + ((lq & 1) << 2)) = o;
            }
        }
    }
    __syncthreads();

    // ---- phase 2: acc2[mt][nt] = W1[d]^T (cols 64w+16mt..) . h1^T (rows 16nt..)
    floatx4 acc2[4][4] = {};
    {
        const __bf16* W1b = W1p + ((size_t)(d * 32 + w * 4) * 16) * 512 + (size_t)lane16 * 8;
        const __bf16* h1b = h1s + lc * HH;
#pragma unroll
        for (int ks = 0; ks < 16; ks++) {
            bf16x8 wf[4];
#pragma unroll
            for (int mt = 0; mt < 4; mt++)
                wf[mt] = *(const bf16x8*)(W1b + (size_t)(mt * 16 + ks) * 512);
            const int hoff = ((4 * ks + lq) ^ sw) << 3;
#pragma unroll
            for (int nt = 0; nt < 4; nt++) {
                bf16x8 hf = *(const bf16x8*)(h1b + 16 * nt * HH + hoff);
#pragma unroll
                for (int mt = 0; mt < 4; mt++)
                    acc2[mt][nt] = __builtin_amdgcn_mfma_f32_16x16x32_bf16(
                        wf[mt], hf, acc2[mt][nt], 0, 0, 0);
            }
        }
    }

    // ---- phase 3: out = leaky(h2) @ W2[d]; lane lc holds rows 16nt+lc
    {
        const float* W2b = W2 + (size_t)d * HH + w * 64 + lq * 4;
#pragma unroll
        for (int nt = 0; nt < 4; nt++) {
            float s = 0.f;
#pragma unroll
            for (int mt = 0; mt < 4; mt++) {
                floatx4 w2q = *(const floatx4*)(W2b + mt * 16);
#pragma unroll
                for (int g = 0; g < 4; g++) {
                    float v = acc2[mt][nt][g];
                    s += fmaxf(v, 0.01f * v) * w2q[g];
                }
            }
            // sum the 4 lq-groups holding the same row
            s += __shfl_xor(s, 16, 64);
            s += __shfl_xor(s, 32, 64);
            if (l < 16) atomicAdd(&outp[16 * nt + lc], s);   // cross-wave reduce
        }
    }
    __syncthreads();
    if (tid < NT) out[(size_t)(n0 + tid) * DD + d] = outp[tid];
}

// ---------------------------------------------------------------------------
extern "C" void kernel_launch(void* const* d_in, const int* in_sizes, int n_in,
                              void* d_out, int out_size, void* d_ws, size_t ws_size,
                              hipStream_t stream) {
    const float* x  = (const float*)d_in[0];
    const float* W0 = (const float*)d_in[1];
    const float* W1 = (const float*)d_in[2];
    const float* W2 = (const float*)d_in[3];
    float* out = (float*)d_out;

    __bf16* W0p = (__bf16*)d_ws;                                          // 16.8 MB
    __bf16* W1p = (__bf16*)((char*)d_ws + (size_t)DD * DD * HH * 2);      // 67.1 MB
    __bf16* xb  = (__bf16*)((char*)d_ws + (size_t)DD * DD * HH * 2
                                        + (size_t)DD * HH * HH * 2);      // 0.5 MB

    cvt_x<<<dim3(NN * DD / (256 * 4)), 256, 0, stream>>>(x, xb);
    pack_w<<<dim3(DD * (DD / 32)), 256, 0, stream>>>(W0, W0p, DD / 32);   // 512 blocks
    pack_w<<<dim3(DD * (HH / 32)), 256, 0, stream>>>(W1, W1p, HH / 32);   // 2048 blocks

    grandag_main<<<dim3(DD * (NN / NT)), 512, 0, stream>>>(xb, W0p, W1p, W2, out);
}